// Round 1
// 1422.036 us; speedup vs baseline: 2.8595x; 2.8595x over previous
//
#include <hip/hip_runtime.h>
#include <hip/hip_bf16.h>

// Problem constants (fixed by the reference)
#define NROWS 38912   // B*NPTS = 2048*19
#define NDIM  256
#define NBOOK 2048
#define BR    64      // rows per block = 4 waves x 16 rows
#define BM    32      // codebook codes per tile
#define NT    (NBOOK/BM)
#define EPSF  1e-10f

typedef __hip_bfloat16 bf16;
typedef short  short8 __attribute__((ext_vector_type(8)));
typedef __bf16 bf16x8 __attribute__((ext_vector_type(8)));
typedef float  f32x4  __attribute__((ext_vector_type(4)));

__device__ __forceinline__ float bf2f(unsigned int u16) {
    union { unsigned int i; float f; } c;
    c.i = u16 << 16;
    return c.f;
}
__device__ __forceinline__ unsigned short f2bf(float v) {
    bf16 h = __float2bfloat16(v);      // RNE
    unsigned short s;
    __builtin_memcpy(&s, &h, 2);
    return s;
}

// D = A*B + C, 16x16x32 bf16. Frags as short8 bit-patterns.
__device__ __forceinline__ f32x4 mfma16(short8 a, short8 b, f32x4 c) {
    return __builtin_amdgcn_mfma_f32_16x16x32_bf16(
        __builtin_bit_cast(bf16x8, a), __builtin_bit_cast(bf16x8, b), c, 0, 0, 0);
}

// ---- dtype-agnostic accessors -------------------------------------------
template<bool BF>
__device__ __forceinline__ float ld1(const void* p, long i) {
    if constexpr (BF) return bf2f(((const unsigned short*)p)[i]);
    else              return ((const float*)p)[i];
}
template<bool BF>
__device__ __forceinline__ void st1(void* p, long i, float v) {
    if constexpr (BF) ((bf16*)p)[i] = __float2bfloat16(v);
    else              ((float*)p)[i] = v;
}
template<bool BF>   // 8 consecutive elements, i multiple of 8
__device__ __forceinline__ void ld8v(const void* p, long i, float* o) {
    if constexpr (BF) {
        uint4 v = *(const uint4*)((const unsigned short*)p + i);
        o[0]=bf2f(v.x&0xffffu); o[1]=bf2f(v.x>>16);
        o[2]=bf2f(v.y&0xffffu); o[3]=bf2f(v.y>>16);
        o[4]=bf2f(v.z&0xffffu); o[5]=bf2f(v.z>>16);
        o[6]=bf2f(v.w&0xffffu); o[7]=bf2f(v.w>>16);
    } else {
        float4 a = *(const float4*)((const float*)p + i);
        float4 b = *(const float4*)((const float*)p + i + 4);
        o[0]=a.x; o[1]=a.y; o[2]=a.z; o[3]=a.w;
        o[4]=b.x; o[5]=b.y; o[6]=b.z; o[7]=b.w;
    }
}
template<bool BF>   // 4 consecutive elements, i multiple of 4
__device__ __forceinline__ void ld4v(const void* p, long i, float* o) {
    if constexpr (BF) {
        uint2 v = *(const uint2*)((const unsigned short*)p + i);
        o[0]=bf2f(v.x&0xffffu); o[1]=bf2f(v.x>>16);
        o[2]=bf2f(v.y&0xffffu); o[3]=bf2f(v.y>>16);
    } else {
        float4 a = *(const float4*)((const float*)p + i);
        o[0]=a.x; o[1]=a.y; o[2]=a.z; o[3]=a.w;
    }
}
template<bool BF>   // 8 consecutive elements store (logits). OUT base is odd ->
                    // f32: dwordx4 at 4B align (arch-legal); bf16: scalar (2B align).
__device__ __forceinline__ void st8v(void* p, long i, const float* v) {
    if constexpr (BF) {
#pragma unroll
        for (int j = 0; j < 8; ++j) ((bf16*)p)[i + j] = __float2bfloat16(v[j]);
    } else {
        float* f = (float*)p + i;
        *(float4*)(f)     = make_float4(v[0], v[1], v[2], v[3]);
        *(float4*)(f + 4) = make_float4(v[4], v[5], v[6], v[7]);
    }
}
template<bool BF>
__device__ __forceinline__ float ldscal(const void* p) {
    if constexpr (BF) return bf2f(*(const unsigned short*)p);
    else              return *(const float*)p;
}

// ---- runtime dtype sniffers (wave-uniform) -------------------------------
__device__ __forceinline__ bool sniff_arr_bf16(const void* gum) {
    const unsigned short* u = (const unsigned short*)gum;
    bool ok = true;
#pragma unroll
    for (int i = 0; i < 32; ++i) {
        float v = bf2f(u[2 * i]);
        ok = ok && (v >= 0.f) && (v <= 1.f);
    }
    return ok;
}
__device__ __forceinline__ bool sniff_scal_bf16(const void* temp) {
    return ((const unsigned short*)temp)[0] != 0;
}

// ---------------------------------------------------------------------------
// Kernel 1: per-code squared norms of the codebook -> d_ws (float[NBOOK])
// ---------------------------------------------------------------------------
template<bool ABF>
__device__ void book_norm_impl(const void* book, float* bbv)
{
    int j = blockIdx.x * blockDim.x + threadIdx.x;
    if (j >= NBOOK) return;
    float s = 0.f;
#pragma unroll 4
    for (int c = 0; c < NDIM; c += 8) {
        float b[8];
        ld8v<ABF>(book, (long)j * NDIM + c, b);
#pragma unroll
        for (int q = 0; q < 8; ++q) s += b[q] * b[q];
    }
    bbv[j] = s;
}

__global__ void book_norm_kernel(const void* __restrict__ book,
                                 const void* __restrict__ gum,
                                 float* __restrict__ bbv)
{
    if (sniff_arr_bf16(gum)) book_norm_impl<true>(book, bbv);
    else                     book_norm_impl<false>(book, bbv);
}

// ---------------------------------------------------------------------------
// Kernel 2: fused MFMA flash-style pipeline.
//   Per block: 64 rows (4 waves x 16). Loop over 64 tiles of 32 codes:
//     stage book tile to LDS (bn: code-major for GEMM1-A; bt: dim-major for
//     GEMM2-B), S^T = mfma(book, z^T), shfl-transpose to per-lane
//     8-consecutive-codes, logits out + gumbel in, online softmax (defer-max
//     THR=8), zq-acc += mfma(P, book). f32 path uses bf16 hi/lo splits.
// ---------------------------------------------------------------------------
template<bool ABF, bool SBF>
__device__ void gvq_impl(const void* __restrict__ ze,
                         const void* __restrict__ temp_p,
                         const void* __restrict__ gum,
                         const void* __restrict__ book,
                         const void* __restrict__ logq_p,
                         const float* __restrict__ bbv,
                         void* __restrict__ out,
                         ushort* __restrict__ bnh, ushort* __restrict__ bnl,
                         ushort* __restrict__ bth, ushort* __restrict__ btl)
{
    const int t    = threadIdx.x;
    const int lane = t & 63;
    const int w    = t >> 6;        // wave 0..3 -> rows w*16..w*16+15
    const int lm   = lane & 15;
    const int g    = lane >> 4;
    const long r0  = (long)blockIdx.x * BR;
    const long myrow = r0 + w * 16 + lm;

    float temperature = ldscal<SBF>(temp_p);
    if (!(temperature != 0.0f)) temperature = 1.0f;
    const float param_q = expf(ldscal<SBF>(logq_p));
    const float prec    = 0.5f / fmaxf(param_q, EPSF);
    const float invT    = 1.0f / temperature;

    const long ZQ_N   = (long)NROWS * NDIM;
    const long LG_OFF = ZQ_N + 1;

    // ---- z fragments (GEMM1 B-operand: col = z-row = lm, k-els = dims
    //      32*ks + 8*g + j), plus exact f32 ||z||^2 ----
    short8 zh[8], zl[8];
    float zz = 0.f;
#pragma unroll
    for (int ks = 0; ks < 8; ++ks) {
        float zv[8];
        ld8v<ABF>(ze, myrow * NDIM + 32 * ks + 8 * g, zv);
        short8 h, l;
#pragma unroll
        for (int j = 0; j < 8; ++j) {
            zz += zv[j] * zv[j];
            unsigned short hs = f2bf(zv[j]);
            h[j] = (short)hs;
            if constexpr (!ABF) l[j] = (short)f2bf(zv[j] - bf2f(hs));
        }
        zh[ks] = h;
        if constexpr (!ABF) zl[ks] = l;
    }
    zz += __shfl_xor(zz, 16);
    zz += __shfl_xor(zz, 32);

    float mrun = -3.0e38f, lrun = 0.f;
    f32x4 acc[16];
#pragma unroll
    for (int n = 0; n < 16; ++n) acc[n] = (f32x4){0.f, 0.f, 0.f, 0.f};

    for (int tile = 0; tile < NT; ++tile) {
        const int jt = tile * BM;
        __syncthreads();   // previous tile's LDS reads complete
        // ---- stage bn[32 codes][256 dims], 16B-chunk XOR-swizzle by code ----
        {
            const int c = t >> 3;
            const int x = t & 7;
#pragma unroll
            for (int q = 0; q < 8; ++q) {
                const int d = 4 * x + 32 * q;   // 4 dims per step
                float v[4];
                ld4v<ABF>(book, (long)(jt + c) * NDIM + d, v);
                const int idx = c * 256 + (((d >> 3) ^ (c & 7)) << 3) + (d & 7);
                unsigned short hs[4], ls[4];
#pragma unroll
                for (int j = 0; j < 4; ++j) {
                    hs[j] = f2bf(v[j]);
                    if constexpr (!ABF) ls[j] = f2bf(v[j] - bf2f(hs[j]));
                }
                *(uint2*)&bnh[idx] = make_uint2((uint)hs[0] | ((uint)hs[1] << 16),
                                                (uint)hs[2] | ((uint)hs[3] << 16));
                if constexpr (!ABF)
                    *(uint2*)&bnl[idx] = make_uint2((uint)ls[0] | ((uint)ls[1] << 16),
                                                    (uint)ls[2] | ((uint)ls[3] << 16));
            }
        }
        // ---- stage bt[256 dims][32 codes], 16B-chunk XOR-swizzle by (d>>1)&3.
        //      Thread owns dim-pair {2dp,2dp+1} x 16 codes; coalesced loads,
        //      conflict-free b128 writes. ----
        {
            const int dp = t & 127;
            const int ch = t >> 7;
#pragma unroll
            for (int j = 0; j < 2; ++j) {
                const int kap = 2 * ch + j;     // 8-code chunk index
                uint h0[4] = {0,0,0,0}, h1[4] = {0,0,0,0};
                uint l0[4] = {0,0,0,0}, l1[4] = {0,0,0,0};
#pragma unroll
                for (int i = 0; i < 8; ++i) {
                    const int c = 8 * kap + i;
                    if constexpr (ABF) {
                        uint rv = *(const uint*)((const unsigned short*)book +
                                                 (long)(jt + c) * NDIM + 2 * dp);
                        h0[i >> 1] |= (rv & 0xffffu) << (16 * (i & 1));
                        h1[i >> 1] |= (rv >> 16)     << (16 * (i & 1));
                    } else {
                        float2 rv = *(const float2*)((const float*)book +
                                                     (long)(jt + c) * NDIM + 2 * dp);
                        unsigned short a = f2bf(rv.x), b = f2bf(rv.y);
                        h0[i >> 1] |= (uint)a << (16 * (i & 1));
                        h1[i >> 1] |= (uint)b << (16 * (i & 1));
                        unsigned short la = f2bf(rv.x - bf2f(a));
                        unsigned short lb = f2bf(rv.y - bf2f(b));
                        l0[i >> 1] |= (uint)la << (16 * (i & 1));
                        l1[i >> 1] |= (uint)lb << (16 * (i & 1));
                    }
                }
                const int sw = (kap ^ (dp & 3)) << 3;
                const int i0 = (2 * dp) * 32 + sw;
                const int i1 = (2 * dp + 1) * 32 + sw;
                *(uint4*)&bth[i0] = make_uint4(h0[0], h0[1], h0[2], h0[3]);
                *(uint4*)&bth[i1] = make_uint4(h1[0], h1[1], h1[2], h1[3]);
                if constexpr (!ABF) {
                    *(uint4*)&btl[i0] = make_uint4(l0[0], l0[1], l0[2], l0[3]);
                    *(uint4*)&btl[i1] = make_uint4(l1[0], l1[1], l1[2], l1[3]);
                }
            }
        }
        __syncthreads();

        // ---- GEMM1: S^T[code][zrow] = book_tile . z^T  (hi/lo split) ----
        f32x4 s0 = {0.f,0.f,0.f,0.f}, s1 = {0.f,0.f,0.f,0.f};
#pragma unroll
        for (int ks = 0; ks < 8; ++ks) {
            const int idx0 = lm * 256 + (((4 * ks + g) ^ (lm & 7)) << 3);
            const int idx1 = idx0 + 16 * 256;   // (16+lm)&7 == lm&7
            short8 a0h = *(const short8*)&bnh[idx0];
            short8 a1h = *(const short8*)&bnh[idx1];
            s0 = mfma16(a0h, zh[ks], s0);
            s1 = mfma16(a1h, zh[ks], s1);
            if constexpr (!ABF) {
                short8 a0l = *(const short8*)&bnl[idx0];
                short8 a1l = *(const short8*)&bnl[idx1];
                s0 = mfma16(a0h, zl[ks], s0);
                s0 = mfma16(a0l, zh[ks], s0);
                s1 = mfma16(a1h, zl[ks], s1);
                s1 = mfma16(a1l, zh[ks], s1);
            }
        }

        // ---- route S^T (C-layout: value(msub,r) at lane(lm=row, g), code =
        //      16*msub+4*g+r) -> st8[e] = S[row lm][code 8*g+e] ----
        float st8[8];
        {
            const int bsel = (lane >= 32);             // target msub = g>>1
            const int sl0 = lm + 16 * (2 * (g & 1));   // h = 0 source lane
            const int sl1 = sl0 + 16;                  // h = 1 source lane
#pragma unroll
            for (int r = 0; r < 4; ++r) {
                float u0 = __shfl(s0[r], sl0);
                float u1 = __shfl(s1[r], sl0);
                st8[r] = bsel ? u1 : u0;
                float u2 = __shfl(s0[r], sl1);
                float u3 = __shfl(s1[r], sl1);
                st8[4 + r] = bsel ? u3 : u2;
            }
        }

        // ---- logits out, gumbel in, softmax inputs (8 consecutive codes) ----
        float bb8[8], gu8[8], lg8[8], vv8[8];
        ld8v<false>(bbv, jt + 8 * g, bb8);
        ld8v<ABF>(gum, myrow * (long)NBOOK + jt + 8 * g, gu8);
#pragma unroll
        for (int e = 0; e < 8; ++e) {
            float logit = -(zz + bb8[e] - 2.f * st8[e]) * prec;
            lg8[e] = logit;
            float gn = -__logf(-__logf(gu8[e] + EPSF) + EPSF);
            vv8[e] = (logit + gn) * invT;
        }
        st8v<ABF>(out, LG_OFF + myrow * (long)NBOOK + jt + 8 * g, lg8);

        // ---- online softmax with defer-max (THR = 8) ----
        float tm = vv8[0];
#pragma unroll
        for (int e = 1; e < 8; ++e) tm = fmaxf(tm, vv8[e]);
        tm = fmaxf(tm, __shfl_xor(tm, 16));
        tm = fmaxf(tm, __shfl_xor(tm, 32));
        if (!__all(tm <= mrun + 8.f)) {
            float mnew = fmaxf(mrun, tm);
            float al = __expf(mrun - mnew);
            lrun *= al;
#pragma unroll
            for (int r = 0; r < 4; ++r) {
                float ar = __shfl(al, 4 * g + r);   // alpha for acc-row 4g+r
#pragma unroll
                for (int n = 0; n < 16; ++n) acc[n][r] *= ar;
            }
            mrun = mnew;
        }
        float p8[8], psum = 0.f;
#pragma unroll
        for (int e = 0; e < 8; ++e) { p8[e] = __expf(vv8[e] - mrun); psum += p8[e]; }
        psum += __shfl_xor(psum, 16);
        psum += __shfl_xor(psum, 32);
        lrun += psum;

        // ---- P fragments (A-operand of GEMM2; element e == k-el 8g+e) ----
        short8 ph, pl;
#pragma unroll
        for (int e = 0; e < 8; ++e) {
            unsigned short hs = f2bf(p8[e]);
            ph[e] = (short)hs;
            pl[e] = (short)f2bf(p8[e] - bf2f(hs));
        }

        // ---- GEMM2: zq-acc += P . book_tile ----
#pragma unroll
        for (int n = 0; n < 16; ++n) {
            const int d = 16 * n + lm;
            const int idx = d * 32 + ((g ^ ((d >> 1) & 3)) << 3);
            short8 bh = *(const short8*)&bth[idx];
            acc[n] = mfma16(ph, bh, acc[n]);
            acc[n] = mfma16(pl, bh, acc[n]);
            if constexpr (!ABF) {
                short8 bl = *(const short8*)&btl[idx];
                acc[n] = mfma16(ph, bl, acc[n]);
            }
        }
    }

    // ---- finalize: zq = acc / l ----
    float inv = 1.f / lrun;
#pragma unroll
    for (int r = 0; r < 4; ++r) {
        float ir = __shfl(inv, 4 * g + r);
        const long orow = (r0 + 16 * w + 4 * g + r) * NDIM;
#pragma unroll
        for (int n = 0; n < 16; ++n)
            st1<ABF>(out, orow + 16 * n + lm, acc[n][r] * ir);
    }
    if (blockIdx.x == 0 && t == 0) st1<ABF>(out, ZQ_N, prec);
}

__global__ __launch_bounds__(256, 2)
void gvq_kernel(const void* __restrict__ ze,
                const void* __restrict__ temp_p,
                const void* __restrict__ gum,
                const void* __restrict__ book,
                const void* __restrict__ logq_p,
                const float* __restrict__ bbv,
                void* __restrict__ out)
{
    __shared__ __align__(16) ushort bnh[32 * 256];
    __shared__ __align__(16) ushort bnl[32 * 256];
    __shared__ __align__(16) ushort bth[256 * 32];
    __shared__ __align__(16) ushort btl[256 * 32];

    const bool abf = sniff_arr_bf16(gum);
    const bool sbf = sniff_scal_bf16(temp_p);
    if (abf) {
        if (sbf) gvq_impl<true,  true >(ze, temp_p, gum, book, logq_p, bbv, out, bnh, bnl, bth, btl);
        else     gvq_impl<true,  false>(ze, temp_p, gum, book, logq_p, bbv, out, bnh, bnl, bth, btl);
    } else {
        if (sbf) gvq_impl<false, true >(ze, temp_p, gum, book, logq_p, bbv, out, bnh, bnl, bth, btl);
        else     gvq_impl<false, false>(ze, temp_p, gum, book, logq_p, bbv, out, bnh, bnl, bth, btl);
    }
}

// ---------------------------------------------------------------------------
extern "C" void kernel_launch(void* const* d_in, const int* in_sizes, int n_in,
                              void* d_out, int out_size, void* d_ws, size_t ws_size,
                              hipStream_t stream)
{
    const void* ze   = d_in[0];   // [38912, 256]
    const void* temp = d_in[1];   // [1]
    const void* gum  = d_in[2];   // [38912, 2048]
    const void* book = d_in[3];   // [2048, 256]
    const void* logq = d_in[4];   // [1]
    float* bbv = (float*)d_ws;    // NBOOK floats of scratch

    hipLaunchKernelGGL(book_norm_kernel, dim3(NBOOK / 256), dim3(256), 0, stream,
                       book, gum, bbv);
    hipLaunchKernelGGL(gvq_kernel, dim3(NROWS / BR), dim3(256), 0, stream,
                       ze, temp, gum, book, logq, bbv, d_out);
}

// Round 2
// 1047.965 us; speedup vs baseline: 3.8802x; 1.3570x over previous
//
#include <hip/hip_runtime.h>
#include <hip/hip_bf16.h>

// Problem constants (fixed by the reference)
#define NROWS 38912   // B*NPTS = 2048*19
#define NDIM  256
#define NBOOK 2048
#define BR    64      // rows per block = 4 waves x 16 rows
#define BM    32      // codebook codes per tile
#define NT    (NBOOK/BM)
#define EPSF  1e-10f

// Pre-converted book image: per tile 32768 ushorts (64 KB):
//   [0,8192)      bnh  [32 codes][256 dims] hi, XOR-swizzled
//   [8192,16384)  bnl  same, lo
//   [16384,24576) bth  [256 dims][32 codes] hi, XOR-swizzled
//   [24576,32768) btl  same, lo
#define IMG_TILE_USH 32768
#define IMG_BYTES    ((size_t)NT * IMG_TILE_USH * 2)   // 4 MiB

typedef __hip_bfloat16 bf16;
typedef short  short8 __attribute__((ext_vector_type(8)));
typedef __bf16 bf16x8 __attribute__((ext_vector_type(8)));
typedef float  f32x4  __attribute__((ext_vector_type(4)));

__device__ __forceinline__ float bf2f(unsigned int u16) {
    union { unsigned int i; float f; } c;
    c.i = u16 << 16;
    return c.f;
}
__device__ __forceinline__ unsigned short f2bf(float v) {
    bf16 h = __float2bfloat16(v);      // RNE
    unsigned short s;
    __builtin_memcpy(&s, &h, 2);
    return s;
}

// D = A*B + C, 16x16x32 bf16. Frags as short8 bit-patterns.
__device__ __forceinline__ f32x4 mfma16(short8 a, short8 b, f32x4 c) {
    return __builtin_amdgcn_mfma_f32_16x16x32_bf16(
        __builtin_bit_cast(bf16x8, a), __builtin_bit_cast(bf16x8, b), c, 0, 0, 0);
}

// global -> LDS direct copy, 16 B per lane (wave-uniform LDS base + lane*16).
typedef __attribute__((address_space(1))) const void* as1cv_t;
typedef __attribute__((address_space(3))) void*       as3v_t;
__device__ __forceinline__ void gload_lds16(const ushort* g, ushort* l) {
    __builtin_amdgcn_global_load_lds((as1cv_t)g, (as3v_t)l, 16, 0, 0);
}

// ---- dtype-agnostic accessors -------------------------------------------
template<bool BF>
__device__ __forceinline__ float ld1(const void* p, long i) {
    if constexpr (BF) return bf2f(((const unsigned short*)p)[i]);
    else              return ((const float*)p)[i];
}
template<bool BF>
__device__ __forceinline__ void st1(void* p, long i, float v) {
    if constexpr (BF) ((bf16*)p)[i] = __float2bfloat16(v);
    else              ((float*)p)[i] = v;
}
template<bool BF>   // 8 consecutive elements, i multiple of 8
__device__ __forceinline__ void ld8v(const void* p, long i, float* o) {
    if constexpr (BF) {
        uint4 v = *(const uint4*)((const unsigned short*)p + i);
        o[0]=bf2f(v.x&0xffffu); o[1]=bf2f(v.x>>16);
        o[2]=bf2f(v.y&0xffffu); o[3]=bf2f(v.y>>16);
        o[4]=bf2f(v.z&0xffffu); o[5]=bf2f(v.z>>16);
        o[6]=bf2f(v.w&0xffffu); o[7]=bf2f(v.w>>16);
    } else {
        float4 a = *(const float4*)((const float*)p + i);
        float4 b = *(const float4*)((const float*)p + i + 4);
        o[0]=a.x; o[1]=a.y; o[2]=a.z; o[3]=a.w;
        o[4]=b.x; o[5]=b.y; o[6]=b.z; o[7]=b.w;
    }
}
template<bool BF>   // 4 consecutive elements, i multiple of 4
__device__ __forceinline__ void ld4v(const void* p, long i, float* o) {
    if constexpr (BF) {
        uint2 v = *(const uint2*)((const unsigned short*)p + i);
        o[0]=bf2f(v.x&0xffffu); o[1]=bf2f(v.x>>16);
        o[2]=bf2f(v.y&0xffffu); o[3]=bf2f(v.y>>16);
    } else {
        float4 a = *(const float4*)((const float*)p + i);
        o[0]=a.x; o[1]=a.y; o[2]=a.z; o[3]=a.w;
    }
}
template<bool BF>   // 8 consecutive elements store (logits). OUT base is odd ->
                    // f32: dwordx4 at 4B align (arch-legal); bf16: scalar (2B align).
__device__ __forceinline__ void st8v(void* p, long i, const float* v) {
    if constexpr (BF) {
#pragma unroll
        for (int j = 0; j < 8; ++j) ((bf16*)p)[i + j] = __float2bfloat16(v[j]);
    } else {
        float* f = (float*)p + i;
        *(float4*)(f)     = make_float4(v[0], v[1], v[2], v[3]);
        *(float4*)(f + 4) = make_float4(v[4], v[5], v[6], v[7]);
    }
}
template<bool BF>
__device__ __forceinline__ float ldscal(const void* p) {
    if constexpr (BF) return bf2f(*(const unsigned short*)p);
    else              return *(const float*)p;
}

// ---- runtime dtype sniffers (wave-uniform) -------------------------------
__device__ __forceinline__ bool sniff_arr_bf16(const void* gum) {
    const unsigned short* u = (const unsigned short*)gum;
    bool ok = true;
#pragma unroll
    for (int i = 0; i < 32; ++i) {
        float v = bf2f(u[2 * i]);
        ok = ok && (v >= 0.f) && (v <= 1.f);
    }
    return ok;
}
__device__ __forceinline__ bool sniff_scal_bf16(const void* temp) {
    return ((const unsigned short*)temp)[0] != 0;
}

// ---------------------------------------------------------------------------
// Kernel 0: build the pre-converted, pre-swizzled per-tile book images in ws.
// Byte-identical to what the in-kernel staging of round 1 produced in LDS.
// ---------------------------------------------------------------------------
template<bool ABF>
__device__ void book_img_impl(const void* __restrict__ book,
                              ushort* __restrict__ img)
{
    const int tile = blockIdx.x;
    const int jt   = tile * BM;
    const int t    = threadIdx.x;
    ushort* im = img + (size_t)tile * IMG_TILE_USH;

    // bn region: [32 codes][256 dims], 16B-chunk XOR-swizzle by code
    {
        const int c = t >> 3;
        const int x = t & 7;
#pragma unroll
        for (int q = 0; q < 8; ++q) {
            const int d = 4 * x + 32 * q;
            float v[4];
            ld4v<ABF>(book, (long)(jt + c) * NDIM + d, v);
            const int idx = c * 256 + (((d >> 3) ^ (c & 7)) << 3) + (d & 7);
            unsigned short hs[4], ls[4];
#pragma unroll
            for (int j = 0; j < 4; ++j) {
                hs[j] = f2bf(v[j]);
                if constexpr (!ABF) ls[j] = f2bf(v[j] - bf2f(hs[j]));
            }
            *(uint2*)&im[idx] = make_uint2((uint)hs[0] | ((uint)hs[1] << 16),
                                           (uint)hs[2] | ((uint)hs[3] << 16));
            if constexpr (!ABF)
                *(uint2*)&im[8192 + idx] = make_uint2((uint)ls[0] | ((uint)ls[1] << 16),
                                                      (uint)ls[2] | ((uint)ls[3] << 16));
        }
    }
    // bt region: [256 dims][32 codes], 16B-chunk XOR-swizzle by (d>>1)&3
    {
        const int dp = t & 127;
        const int ch = t >> 7;
#pragma unroll
        for (int j = 0; j < 2; ++j) {
            const int kap = 2 * ch + j;     // 8-code chunk index
            uint h0[4] = {0,0,0,0}, h1[4] = {0,0,0,0};
            uint l0[4] = {0,0,0,0}, l1[4] = {0,0,0,0};
#pragma unroll
            for (int i = 0; i < 8; ++i) {
                const int c = 8 * kap + i;
                if constexpr (ABF) {
                    uint rv = *(const uint*)((const unsigned short*)book +
                                             (long)(jt + c) * NDIM + 2 * dp);
                    h0[i >> 1] |= (rv & 0xffffu) << (16 * (i & 1));
                    h1[i >> 1] |= (rv >> 16)     << (16 * (i & 1));
                } else {
                    float2 rv = *(const float2*)((const float*)book +
                                                 (long)(jt + c) * NDIM + 2 * dp);
                    unsigned short a = f2bf(rv.x), b = f2bf(rv.y);
                    h0[i >> 1] |= (uint)a << (16 * (i & 1));
                    h1[i >> 1] |= (uint)b << (16 * (i & 1));
                    unsigned short la = f2bf(rv.x - bf2f(a));
                    unsigned short lb = f2bf(rv.y - bf2f(b));
                    l0[i >> 1] |= (uint)la << (16 * (i & 1));
                    l1[i >> 1] |= (uint)lb << (16 * (i & 1));
                }
            }
            const int sw = (kap ^ (dp & 3)) << 3;
            const int i0 = (2 * dp) * 32 + sw;
            const int i1 = (2 * dp + 1) * 32 + sw;
            *(uint4*)&im[16384 + i0] = make_uint4(h0[0], h0[1], h0[2], h0[3]);
            *(uint4*)&im[16384 + i1] = make_uint4(h1[0], h1[1], h1[2], h1[3]);
            if constexpr (!ABF) {
                *(uint4*)&im[24576 + i0] = make_uint4(l0[0], l0[1], l0[2], l0[3]);
                *(uint4*)&im[24576 + i1] = make_uint4(l1[0], l1[1], l1[2], l1[3]);
            }
        }
    }
}

__global__ void book_img_kernel(const void* __restrict__ book,
                                const void* __restrict__ gum,
                                ushort* __restrict__ img)
{
    if (sniff_arr_bf16(gum)) book_img_impl<true >(book, img);
    else                     book_img_impl<false>(book, img);
}

// ---------------------------------------------------------------------------
// Kernel 1: per-code squared norms of the codebook -> bbv (float[NBOOK])
// ---------------------------------------------------------------------------
template<bool ABF>
__device__ void book_norm_impl(const void* book, float* bbv)
{
    int j = blockIdx.x * blockDim.x + threadIdx.x;
    if (j >= NBOOK) return;
    float s = 0.f;
#pragma unroll 4
    for (int c = 0; c < NDIM; c += 8) {
        float b[8];
        ld8v<ABF>(book, (long)j * NDIM + c, b);
#pragma unroll
        for (int q = 0; q < 8; ++q) s += b[q] * b[q];
    }
    bbv[j] = s;
}

__global__ void book_norm_kernel(const void* __restrict__ book,
                                 const void* __restrict__ gum,
                                 float* __restrict__ bbv)
{
    if (sniff_arr_bf16(gum)) book_norm_impl<true>(book, bbv);
    else                     book_norm_impl<false>(book, bbv);
}

// ---------------------------------------------------------------------------
// Kernel 2: fused MFMA flash-style pipeline.
//   PRE=1: stage each tile with pure global_load_lds from the precomputed
//   image (no VALU, no ds_writes). PRE=0: round-1 in-kernel staging fallback.
// ---------------------------------------------------------------------------
template<bool ABF, bool SBF, bool PRE>
__device__ void gvq_impl(const void* __restrict__ ze,
                         const void* __restrict__ temp_p,
                         const void* __restrict__ gum,
                         const void* __restrict__ book,
                         const void* __restrict__ logq_p,
                         const float* __restrict__ bbv,
                         const ushort* __restrict__ img,
                         void* __restrict__ out,
                         ushort* __restrict__ lds_u)
{
    const int t    = threadIdx.x;
    const int lane = t & 63;
    const int w    = t >> 6;        // wave 0..3 -> rows w*16..w*16+15
    const int lm   = lane & 15;
    const int g    = lane >> 4;
    const long r0  = (long)blockIdx.x * BR;
    const long myrow = r0 + w * 16 + lm;

    ushort* bnh = lds_u;
    ushort* bnl = lds_u + 8192;
    ushort* bth = lds_u + 16384;
    ushort* btl = lds_u + 24576;

    float temperature = ldscal<SBF>(temp_p);
    if (!(temperature != 0.0f)) temperature = 1.0f;
    const float param_q = expf(ldscal<SBF>(logq_p));
    const float prec    = 0.5f / fmaxf(param_q, EPSF);
    const float invT    = 1.0f / temperature;

    const long ZQ_N   = (long)NROWS * NDIM;
    const long LG_OFF = ZQ_N + 1;

    // ---- z fragments (GEMM1 B-operand: col = z-row = lm, k-els = dims
    //      32*ks + 8*g + j), plus exact f32 ||z||^2 ----
    short8 zh[8], zl[8];
    float zz = 0.f;
#pragma unroll
    for (int ks = 0; ks < 8; ++ks) {
        float zv[8];
        ld8v<ABF>(ze, myrow * NDIM + 32 * ks + 8 * g, zv);
        short8 h, l;
#pragma unroll
        for (int j = 0; j < 8; ++j) {
            zz += zv[j] * zv[j];
            unsigned short hs = f2bf(zv[j]);
            h[j] = (short)hs;
            if constexpr (!ABF) l[j] = (short)f2bf(zv[j] - bf2f(hs));
        }
        zh[ks] = h;
        if constexpr (!ABF) zl[ks] = l;
    }
    zz += __shfl_xor(zz, 16);
    zz += __shfl_xor(zz, 32);

    float mrun = -3.0e38f, lrun = 0.f;
    f32x4 acc[16];
#pragma unroll
    for (int n = 0; n < 16; ++n) acc[n] = (f32x4){0.f, 0.f, 0.f, 0.f};

    for (int tile = 0; tile < NT; ++tile) {
        const int jt = tile * BM;
        __syncthreads();   // previous tile's LDS reads complete

        if constexpr (PRE) {
            // ---- stage whole 64KB (f32) / 32KB (bf16) tile image ----
            const ushort* gsrc = img + (size_t)tile * IMG_TILE_USH;
            if constexpr (!ABF) {
#pragma unroll
                for (int k = 0; k < 16; ++k) {
                    const int off = (w * 16 + k) * 512;   // 1KB chunks
                    gload_lds16(gsrc + off + lane * 8, lds_u + off);
                }
            } else {
#pragma unroll
                for (int k = 0; k < 8; ++k) {
                    const int cid = w * 8 + k;            // 0..31 over hi regions
                    const int off = cid * 512 + (cid >= 16 ? 8192 : 0);
                    gload_lds16(gsrc + off + lane * 8, lds_u + off);
                }
            }
        } else {
            // ---- round-1 in-kernel staging (fallback when ws too small) ----
            {
                const int c = t >> 3;
                const int x = t & 7;
#pragma unroll
                for (int q = 0; q < 8; ++q) {
                    const int d = 4 * x + 32 * q;
                    float v[4];
                    ld4v<ABF>(book, (long)(jt + c) * NDIM + d, v);
                    const int idx = c * 256 + (((d >> 3) ^ (c & 7)) << 3) + (d & 7);
                    unsigned short hs[4], ls[4];
#pragma unroll
                    for (int j = 0; j < 4; ++j) {
                        hs[j] = f2bf(v[j]);
                        if constexpr (!ABF) ls[j] = f2bf(v[j] - bf2f(hs[j]));
                    }
                    *(uint2*)&bnh[idx] = make_uint2((uint)hs[0] | ((uint)hs[1] << 16),
                                                    (uint)hs[2] | ((uint)hs[3] << 16));
                    if constexpr (!ABF)
                        *(uint2*)&bnl[idx] = make_uint2((uint)ls[0] | ((uint)ls[1] << 16),
                                                        (uint)ls[2] | ((uint)ls[3] << 16));
                }
            }
            {
                const int dp = t & 127;
                const int ch = t >> 7;
#pragma unroll
                for (int j = 0; j < 2; ++j) {
                    const int kap = 2 * ch + j;
                    uint h0[4] = {0,0,0,0}, h1[4] = {0,0,0,0};
                    uint l0[4] = {0,0,0,0}, l1[4] = {0,0,0,0};
#pragma unroll
                    for (int i = 0; i < 8; ++i) {
                        const int c = 8 * kap + i;
                        if constexpr (ABF) {
                            uint rv = *(const uint*)((const unsigned short*)book +
                                                     (long)(jt + c) * NDIM + 2 * dp);
                            h0[i >> 1] |= (rv & 0xffffu) << (16 * (i & 1));
                            h1[i >> 1] |= (rv >> 16)     << (16 * (i & 1));
                        } else {
                            float2 rv = *(const float2*)((const float*)book +
                                                         (long)(jt + c) * NDIM + 2 * dp);
                            unsigned short a = f2bf(rv.x), b = f2bf(rv.y);
                            h0[i >> 1] |= (uint)a << (16 * (i & 1));
                            h1[i >> 1] |= (uint)b << (16 * (i & 1));
                            unsigned short la = f2bf(rv.x - bf2f(a));
                            unsigned short lb = f2bf(rv.y - bf2f(b));
                            l0[i >> 1] |= (uint)la << (16 * (i & 1));
                            l1[i >> 1] |= (uint)lb << (16 * (i & 1));
                        }
                    }
                    const int sw = (kap ^ (dp & 3)) << 3;
                    const int i0 = (2 * dp) * 32 + sw;
                    const int i1 = (2 * dp + 1) * 32 + sw;
                    *(uint4*)&bth[i0] = make_uint4(h0[0], h0[1], h0[2], h0[3]);
                    *(uint4*)&bth[i1] = make_uint4(h1[0], h1[1], h1[2], h1[3]);
                    if constexpr (!ABF) {
                        *(uint4*)&btl[i0] = make_uint4(l0[0], l0[1], l0[2], l0[3]);
                        *(uint4*)&btl[i1] = make_uint4(l1[0], l1[1], l1[2], l1[3]);
                    }
                }
            }
        }

        // ---- hoisted gumbel + book-norm loads (latency hides under drain) ----
        float gu8[8], bb8[8];
        ld8v<ABF>(gum, myrow * (long)NBOOK + jt + 8 * g, gu8);
        ld8v<false>(bbv, jt + 8 * g, bb8);

        __syncthreads();   // staged tile visible (drains vmcnt+lgkmcnt)

        // ---- GEMM1: S^T[code][zrow] = book_tile . z^T, 4 independent chains ----
        f32x4 p0[2], p1[2];
#pragma unroll
        for (int c = 0; c < 2; ++c) {
            p0[c] = (f32x4){0.f,0.f,0.f,0.f};
            p1[c] = (f32x4){0.f,0.f,0.f,0.f};
        }
#pragma unroll
        for (int ks = 0; ks < 8; ++ks) {
            const int sel = ks & 1;
            const int idx0 = lm * 256 + (((4 * ks + g) ^ (lm & 7)) << 3);
            const int idx1 = idx0 + 16 * 256;   // (16+lm)&7 == lm&7
            short8 a0h = *(const short8*)&bnh[idx0];
            short8 a1h = *(const short8*)&bnh[idx1];
            p0[sel] = mfma16(a0h, zh[ks], p0[sel]);
            p1[sel] = mfma16(a1h, zh[ks], p1[sel]);
            if constexpr (!ABF) {
                short8 a0l = *(const short8*)&bnl[idx0];
                short8 a1l = *(const short8*)&bnl[idx1];
                p0[sel] = mfma16(a0h, zl[ks], p0[sel]);
                p0[sel] = mfma16(a0l, zh[ks], p0[sel]);
                p1[sel] = mfma16(a1h, zl[ks], p1[sel]);
                p1[sel] = mfma16(a1l, zh[ks], p1[sel]);
            }
        }
        f32x4 s0 = p0[0] + p0[1];
        f32x4 s1 = p1[0] + p1[1];

        // ---- route S^T (C-layout: value(msub,r) at lane(lm=row, g), code =
        //      16*msub+4*g+r) -> st8[e] = S[row lm][code 8*g+e] ----
        float st8[8];
        {
            const int bsel = (lane >= 32);             // target msub = g>>1
            const int sl0 = lm + 16 * (2 * (g & 1));   // h = 0 source lane
            const int sl1 = sl0 + 16;                  // h = 1 source lane
#pragma unroll
            for (int r = 0; r < 4; ++r) {
                float u0 = __shfl(s0[r], sl0);
                float u1 = __shfl(s1[r], sl0);
                st8[r] = bsel ? u1 : u0;
                float u2 = __shfl(s0[r], sl1);
                float u3 = __shfl(s1[r], sl1);
                st8[4 + r] = bsel ? u3 : u2;
            }
        }

        // ---- logits out, gumbel noise, softmax inputs ----
        float lg8[8], vv8[8];
#pragma unroll
        for (int e = 0; e < 8; ++e) {
            float logit = -(zz + bb8[e] - 2.f * st8[e]) * prec;
            lg8[e] = logit;
            float gn = -__logf(-__logf(gu8[e] + EPSF) + EPSF);
            vv8[e] = (logit + gn) * invT;
        }
        st8v<ABF>(out, LG_OFF + myrow * (long)NBOOK + jt + 8 * g, lg8);

        // ---- online softmax with defer-max (THR = 8) ----
        float tm = vv8[0];
#pragma unroll
        for (int e = 1; e < 8; ++e) tm = fmaxf(tm, vv8[e]);
        tm = fmaxf(tm, __shfl_xor(tm, 16));
        tm = fmaxf(tm, __shfl_xor(tm, 32));
        if (!__all(tm <= mrun + 8.f)) {
            float mnew = fmaxf(mrun, tm);
            float al = __expf(mrun - mnew);
            lrun *= al;
#pragma unroll
            for (int r = 0; r < 4; ++r) {
                float ar = __shfl(al, 4 * g + r);   // alpha for acc-row 4g+r
#pragma unroll
                for (int n = 0; n < 16; ++n) acc[n][r] *= ar;
            }
            mrun = mnew;
        }
        float p8[8], psum = 0.f;
#pragma unroll
        for (int e = 0; e < 8; ++e) { p8[e] = __expf(vv8[e] - mrun); psum += p8[e]; }
        psum += __shfl_xor(psum, 16);
        psum += __shfl_xor(psum, 32);
        lrun += psum;

        // ---- P fragments (A-operand of GEMM2; element e == k-el 8g+e) ----
        short8 ph, pl;
#pragma unroll
        for (int e = 0; e < 8; ++e) {
            unsigned short hs = f2bf(p8[e]);
            ph[e] = (short)hs;
            pl[e] = (short)f2bf(p8[e] - bf2f(hs));
        }

        // ---- GEMM2: zq-acc += P . book_tile ----
#pragma unroll
        for (int n = 0; n < 16; ++n) {
            const int d = 16 * n + lm;
            const int idx = d * 32 + ((g ^ ((d >> 1) & 3)) << 3);
            short8 bh = *(const short8*)&bth[idx];
            acc[n] = mfma16(ph, bh, acc[n]);
            acc[n] = mfma16(pl, bh, acc[n]);
            if constexpr (!ABF) {
                short8 bl = *(const short8*)&btl[idx];
                acc[n] = mfma16(ph, bl, acc[n]);
            }
        }
    }

    // ---- finalize: zq = acc / l ----
    float inv = 1.f / lrun;
#pragma unroll
    for (int r = 0; r < 4; ++r) {
        float ir = __shfl(inv, 4 * g + r);
        const long orow = (r0 + 16 * w + 4 * g + r) * NDIM;
#pragma unroll
        for (int n = 0; n < 16; ++n)
            st1<ABF>(out, orow + 16 * n + lm, acc[n][r] * ir);
    }
    if (blockIdx.x == 0 && t == 0) st1<ABF>(out, ZQ_N, prec);
}

__global__ __launch_bounds__(256, 2)
void gvq_kernel(const void* __restrict__ ze,
                const void* __restrict__ temp_p,
                const void* __restrict__ gum,
                const void* __restrict__ book,
                const void* __restrict__ logq_p,
                const float* __restrict__ bbv,
                const ushort* __restrict__ img,
                int pre,
                void* __restrict__ out)
{
    __shared__ __align__(16) ushort lds_u[IMG_TILE_USH];   // 64 KB

    const bool abf = sniff_arr_bf16(gum);
    const bool sbf = sniff_scal_bf16(temp_p);
    if (pre) {
        if (abf) {
            if (sbf) gvq_impl<true,  true,  true>(ze, temp_p, gum, book, logq_p, bbv, img, out, lds_u);
            else     gvq_impl<true,  false, true>(ze, temp_p, gum, book, logq_p, bbv, img, out, lds_u);
        } else {
            if (sbf) gvq_impl<false, true,  true>(ze, temp_p, gum, book, logq_p, bbv, img, out, lds_u);
            else     gvq_impl<false, false, true>(ze, temp_p, gum, book, logq_p, bbv, img, out, lds_u);
        }
    } else {
        if (abf) {
            if (sbf) gvq_impl<true,  true,  false>(ze, temp_p, gum, book, logq_p, bbv, img, out, lds_u);
            else     gvq_impl<true,  false, false>(ze, temp_p, gum, book, logq_p, bbv, img, out, lds_u);
        } else {
            if (sbf) gvq_impl<false, true,  false>(ze, temp_p, gum, book, logq_p, bbv, img, out, lds_u);
            else     gvq_impl<false, false, false>(ze, temp_p, gum, book, logq_p, bbv, img, out, lds_u);
        }
    }
}

// ---------------------------------------------------------------------------
extern "C" void kernel_launch(void* const* d_in, const int* in_sizes, int n_in,
                              void* d_out, int out_size, void* d_ws, size_t ws_size,
                              hipStream_t stream)
{
    const void* ze   = d_in[0];   // [38912, 256]
    const void* temp = d_in[1];   // [1]
    const void* gum  = d_in[2];   // [38912, 2048]
    const void* book = d_in[3];   // [2048, 256]
    const void* logq = d_in[4];   // [1]

    const int pre = (ws_size >= IMG_BYTES + NBOOK * sizeof(float)) ? 1 : 0;
    ushort* img = (ushort*)d_ws;
    float*  bbv = (float*)((char*)d_ws + (pre ? IMG_BYTES : 0));

    if (pre)
        hipLaunchKernelGGL(book_img_kernel, dim3(NT), dim3(256), 0, stream,
                           book, gum, img);
    hipLaunchKernelGGL(book_norm_kernel, dim3(NBOOK / 256), dim3(256), 0, stream,
                       book, gum, bbv);
    hipLaunchKernelGGL(gvq_kernel, dim3(NROWS / BR), dim3(256), 0, stream,
                       ze, temp, gum, book, logq, bbv, img, pre, d_out);
}